// Round 2
// baseline (421.188 us; speedup 1.0000x reference)
//
#include <hip/hip_runtime.h>
#include <hip/hip_bf16.h>

typedef __attribute__((ext_vector_type(8))) _Float16 f16x8;
typedef __attribute__((ext_vector_type(4))) _Float16 f16x4;
typedef __attribute__((ext_vector_type(4))) float f32x4;

// ---------------------------------------------------------------- cast f32 -> f16
__global__ __launch_bounds__(256) void cast_f32_f16(const float* __restrict__ s,
                                                    _Float16* __restrict__ d, int n) {
  int i = (blockIdx.x * blockDim.x + threadIdx.x) * 4;
  if (i >= n) return;
  float4 v = *reinterpret_cast<const float4*>(s + i);
  f16x4 h = {(_Float16)v.x, (_Float16)v.y, (_Float16)v.z, (_Float16)v.w};
  *reinterpret_cast<f16x4*>(d + i) = h;
}

// ---------------------------------------------------------------- GEMM C = A @ B^T + bias
// A [M,K] f16 row-major, Bm [N,K] f16 row-major. 128x128 tile, BK=32, 4 waves (2x2 of 64x64).
// EPI=0: scatter to Q (scaled by 0.125) [bh][L][64], K [bh][L][64], Vt [bh][64][L] (f16)
// EPI=1: Cout[M,N] fp32
template <int EPI>
__global__ __launch_bounds__(256) void gemm_bt(
    const _Float16* __restrict__ A, const _Float16* __restrict__ Bm,
    const float* __restrict__ bias, float* __restrict__ Cout,
    _Float16* __restrict__ Qo, _Float16* __restrict__ Ko, _Float16* __restrict__ Vto,
    int Ndim, int Kdim) {
  __shared__ __align__(16) _Float16 As[128][40];
  __shared__ __align__(16) _Float16 Bs[128][40];
  const int tid = threadIdx.x;
  const int lane = tid & 63;
  const int wave = tid >> 6;
  const int wm = wave >> 1, wn = wave & 1;
  const int m0 = blockIdx.y * 128, n0 = blockIdx.x * 128;
  const int r = tid >> 2;
  const int kc = (tid & 3) * 8;
  const int row = lane & 15;
  const int kk = (lane >> 4) * 8;

  f32x4 acc[4][4];
#pragma unroll
  for (int i = 0; i < 4; ++i)
#pragma unroll
    for (int j = 0; j < 4; ++j)
#pragma unroll
      for (int q = 0; q < 4; ++q) acc[i][j][q] = 0.f;

  for (int k0 = 0; k0 < Kdim; k0 += 32) {
    *reinterpret_cast<uint4*>(&As[r][kc]) =
        *reinterpret_cast<const uint4*>(&A[(size_t)(m0 + r) * Kdim + k0 + kc]);
    *reinterpret_cast<uint4*>(&As[r + 64][kc]) =
        *reinterpret_cast<const uint4*>(&A[(size_t)(m0 + r + 64) * Kdim + k0 + kc]);
    *reinterpret_cast<uint4*>(&Bs[r][kc]) =
        *reinterpret_cast<const uint4*>(&Bm[(size_t)(n0 + r) * Kdim + k0 + kc]);
    *reinterpret_cast<uint4*>(&Bs[r + 64][kc]) =
        *reinterpret_cast<const uint4*>(&Bm[(size_t)(n0 + r + 64) * Kdim + k0 + kc]);
    __syncthreads();
    f16x8 af[4], bf[4];
#pragma unroll
    for (int i = 0; i < 4; ++i)
      af[i] = *reinterpret_cast<const f16x8*>(&As[wm * 64 + i * 16 + row][kk]);
#pragma unroll
    for (int j = 0; j < 4; ++j)
      bf[j] = *reinterpret_cast<const f16x8*>(&Bs[wn * 64 + j * 16 + row][kk]);
#pragma unroll
    for (int i = 0; i < 4; ++i)
#pragma unroll
      for (int j = 0; j < 4; ++j)
        acc[i][j] = __builtin_amdgcn_mfma_f32_16x16x32_f16(af[i], bf[j], acc[i][j], 0, 0, 0);
    __syncthreads();
  }

#pragma unroll
  for (int i = 0; i < 4; ++i) {
#pragma unroll
    for (int j = 0; j < 4; ++j) {
#pragma unroll
      for (int q = 0; q < 4; ++q) {
        const int gm = m0 + wm * 64 + i * 16 + (lane >> 4) * 4 + q;
        const int gn = n0 + wn * 64 + j * 16 + row;
        const float c = acc[i][j][q] + bias[gn];
        if (EPI == 1) {
          Cout[(size_t)gm * Ndim + gn] = c;
        } else {
          const int b = gm >> 11, l = gm & 2047;
          const int part = gn >> 10, dD = gn & 1023;
          const int h = dD >> 6, dd = dD & 63;
          const int bh = b * 16 + h;
          if (part == 0)
            Qo[((size_t)bh * 2048 + l) * 64 + dd] = (_Float16)(c * 0.125f);  // fold 1/sqrt(hd)
          else if (part == 1)
            Ko[((size_t)bh * 2048 + l) * 64 + dd] = (_Float16)c;
          else
            Vto[((size_t)bh * 64 + dd) * 2048 + l] = (_Float16)c;
        }
      }
    }
  }
}

// ---------------------------------------------------------------- flash attention v2
// Swapped QK^T (S^T in regs, lane-local softmax) + PV via K=16 MFMA whose B-frag
// layout equals the S^T output layout: NO LDS, NO barriers, waves fully independent.
// grid: 32 bh * 32 qtiles, 4 waves/block, each wave owns 16 q-rows.
__global__ __launch_bounds__(256) void attn_fwd(const _Float16* __restrict__ Qh,
                                                const _Float16* __restrict__ Kh,
                                                const _Float16* __restrict__ Vth,
                                                _Float16* __restrict__ AOh) {
  const int tid = threadIdx.x, lane = tid & 63, wave = tid >> 6;
  const int bh = blockIdx.x >> 5;
  const int q0 = (blockIdx.x & 31) * 64 + wave * 16;
  const int b = bh >> 4, h = bh & 15;
  const _Float16* Qp = Qh + ((size_t)bh * 2048 + q0) * 64;
  const _Float16* Kp = Kh + (size_t)bh * 2048 * 64;
  const _Float16* Vp = Vth + (size_t)bh * 64 * 2048;
  const int r16 = lane & 15;   // this lane's q-row (and A-frag row)
  const int g = lane >> 4;     // 4-lane group
  const int kk8 = g * 8;
  const int kk4 = g * 4;

  // Q as B-fragment: lane holds Q[q=r16][d = kk8..kk8+7] (+32 for second half)
  const f16x8 qf0 = *reinterpret_cast<const f16x8*>(&Qp[r16 * 64 + kk8]);
  const f16x8 qf1 = *reinterpret_cast<const f16x8*>(&Qp[r16 * 64 + 32 + kk8]);

  f32x4 o[4];  // O^T acc: o[n][reg] = O^T[hd=n*16+kk4+reg][q=r16]
#pragma unroll
  for (int n = 0; n < 4; ++n)
#pragma unroll
    for (int q = 0; q < 4; ++q) o[n][q] = 0.f;
  float mrun = -1e30f, lrun = 0.f;

  // K A-fragments for current tile: kc[t*2+dh] = K[kv + t*16 + r16][dh*32 + kk8 ..+7]
  f16x8 kc0 = *reinterpret_cast<const f16x8*>(&Kp[(size_t)(r16)*64 + kk8]);
  f16x8 kc1 = *reinterpret_cast<const f16x8*>(&Kp[(size_t)(r16)*64 + 32 + kk8]);
  f16x8 kc2 = *reinterpret_cast<const f16x8*>(&Kp[(size_t)(16 + r16) * 64 + kk8]);
  f16x8 kc3 = *reinterpret_cast<const f16x8*>(&Kp[(size_t)(16 + r16) * 64 + 32 + kk8]);

#pragma unroll 2
  for (int kv = 0; kv < 2048; kv += 32) {
    const int kvn = (kv + 32) & 2047;  // wrap: last-iter prefetch reads valid mem, unused
    // V A-fragments for this tile (issue early, independent of softmax)
    f16x4 vf[4][2];
#pragma unroll
    for (int n = 0; n < 4; ++n)
#pragma unroll
      for (int t = 0; t < 2; ++t)
        vf[n][t] = *reinterpret_cast<const f16x4*>(
            &Vp[(size_t)(n * 16 + r16) * 2048 + kv + t * 16 + kk4]);
    // prefetch next K tile
    const f16x8 kn0 = *reinterpret_cast<const f16x8*>(&Kp[(size_t)(kvn + r16) * 64 + kk8]);
    const f16x8 kn1 = *reinterpret_cast<const f16x8*>(&Kp[(size_t)(kvn + r16) * 64 + 32 + kk8]);
    const f16x8 kn2 = *reinterpret_cast<const f16x8*>(&Kp[(size_t)(kvn + 16 + r16) * 64 + kk8]);
    const f16x8 kn3 =
        *reinterpret_cast<const f16x8*>(&Kp[(size_t)(kvn + 16 + r16) * 64 + 32 + kk8]);

    // S^T = K . Q^T : lane holds S[q=r16][k = kv + t*16 + kk4 + reg]
    f32x4 s0 = {0.f, 0.f, 0.f, 0.f}, s1 = {0.f, 0.f, 0.f, 0.f};
    s0 = __builtin_amdgcn_mfma_f32_16x16x32_f16(kc0, qf0, s0, 0, 0, 0);
    s0 = __builtin_amdgcn_mfma_f32_16x16x32_f16(kc1, qf1, s0, 0, 0, 0);
    s1 = __builtin_amdgcn_mfma_f32_16x16x32_f16(kc2, qf0, s1, 0, 0, 0);
    s1 = __builtin_amdgcn_mfma_f32_16x16x32_f16(kc3, qf1, s1, 0, 0, 0);

    // lane-local online softmax for q = r16 (4 lanes share q: xor16, xor32)
    float mt = fmaxf(fmaxf(fmaxf(s0[0], s0[1]), fmaxf(s0[2], s0[3])),
                     fmaxf(fmaxf(s1[0], s1[1]), fmaxf(s1[2], s1[3])));
    mt = fmaxf(mt, __shfl_xor(mt, 16));
    mt = fmaxf(mt, __shfl_xor(mt, 32));
    const float mn = fmaxf(mrun, mt);
    const float alpha = __expf(mrun - mn);
    mrun = mn;
    float p[8];
#pragma unroll
    for (int q = 0; q < 4; ++q) p[q] = __expf(s0[q] - mn);
#pragma unroll
    for (int q = 0; q < 4; ++q) p[4 + q] = __expf(s1[q] - mn);
    float rs = ((p[0] + p[1]) + (p[2] + p[3])) + ((p[4] + p[5]) + (p[6] + p[7]));
    rs += __shfl_xor(rs, 16);
    rs += __shfl_xor(rs, 32);
    lrun = lrun * alpha + rs;
#pragma unroll
    for (int n = 0; n < 4; ++n)
#pragma unroll
      for (int q = 0; q < 4; ++q) o[n][q] *= alpha;
    // pack P to f16: element j of pk_t is k = kv + t*16 + kk4 + j  (== K=16 B-frag layout)
    f16x4 pk0, pk1;
#pragma unroll
    for (int q = 0; q < 4; ++q) pk0[q] = (_Float16)p[q];
#pragma unroll
    for (int q = 0; q < 4; ++q) pk1[q] = (_Float16)p[4 + q];
    // O^T += V^T . P^T  (two K=16 MFMAs per hd-tile)
#pragma unroll
    for (int n = 0; n < 4; ++n) {
      o[n] = __builtin_amdgcn_mfma_f32_16x16x16f16(vf[n][0], pk0, o[n], 0, 0, 0);
      o[n] = __builtin_amdgcn_mfma_f32_16x16x16f16(vf[n][1], pk1, o[n], 0, 0, 0);
    }
    kc0 = kn0; kc1 = kn1; kc2 = kn2; kc3 = kn3;
  }

  const float inv = 1.f / lrun;
  const size_t grow = (size_t)b * 2048 + q0 + r16;
#pragma unroll
  for (int n = 0; n < 4; ++n) {
    f16x4 c;
#pragma unroll
    for (int q = 0; q < 4; ++q) c[q] = (_Float16)(o[n][q] * inv);
    *reinterpret_cast<f16x4*>(&AOh[grow * 1024 + h * 64 + n * 16 + kk4]) = c;
  }
}

// ---------------------------------------------------------------- launcher
extern "C" void kernel_launch(void* const* d_in, const int* in_sizes, int n_in, void* d_out,
                              int out_size, void* d_ws, size_t ws_size, hipStream_t stream) {
  const float* x = (const float*)d_in[0];
  const float* Wqkv = (const float*)d_in[1];
  const float* bqkv = (const float*)d_in[2];
  const float* Wout = (const float*)d_in[3];
  const float* bout = (const float*)d_in[4];
  float* out = (float*)d_out;

  char* ws = (char*)d_ws;
  _Float16* xh = (_Float16*)(ws);                  // 4096*1024       (8 MB)
  _Float16* wqkvh = (_Float16*)(ws + 8388608);     // 3072*1024       (6 MB)
  _Float16* wouth = (_Float16*)(ws + 14680064);    // 1024*1024       (2 MB)
  _Float16* Qh = (_Float16*)(ws + 16777216);       // [32][2048][64]  (8 MB)
  _Float16* Kh = (_Float16*)(ws + 25165824);       // [32][2048][64]  (8 MB)
  _Float16* Vth = (_Float16*)(ws + 33554432);      // [32][64][2048]  (8 MB)
  _Float16* AOh = (_Float16*)(ws + 41943040);      // 4096*1024       (8 MB)

  cast_f32_f16<<<4096, 256, 0, stream>>>(x, xh, 4194304);
  cast_f32_f16<<<3072, 256, 0, stream>>>(Wqkv, wqkvh, 3145728);
  cast_f32_f16<<<1024, 256, 0, stream>>>(Wout, wouth, 1048576);

  gemm_bt<0><<<dim3(24, 32), 256, 0, stream>>>(xh, wqkvh, bqkv, nullptr, Qh, Kh, Vth, 3072, 1024);
  attn_fwd<<<1024, 256, 0, stream>>>(Qh, Kh, Vth, AOh);
  gemm_bt<1><<<dim3(8, 32), 256, 0, stream>>>(AOh, wouth, bout, out, nullptr, nullptr, nullptr,
                                              1024, 1024);
}

// Round 3
// 172.873 us; speedup vs baseline: 2.4364x; 2.4364x over previous
//
#include <hip/hip_runtime.h>
#include <hip/hip_bf16.h>

typedef __attribute__((ext_vector_type(8))) _Float16 f16x8;
typedef __attribute__((ext_vector_type(4))) _Float16 f16x4;
typedef __attribute__((ext_vector_type(4))) float f32x4;

// ---------------------------------------------------------------- cast f32 -> f16
__global__ __launch_bounds__(256) void cast_f32_f16(const float* __restrict__ s,
                                                    _Float16* __restrict__ d, int n) {
  int i = (blockIdx.x * blockDim.x + threadIdx.x) * 4;
  if (i >= n) return;
  float4 v = *reinterpret_cast<const float4*>(s + i);
  f16x4 h = {(_Float16)v.x, (_Float16)v.y, (_Float16)v.z, (_Float16)v.w};
  *reinterpret_cast<f16x4*>(d + i) = h;
}

// ---------------------------------------------------------------- GEMM C = A @ B^T + bias
template <int EPI>
__global__ __launch_bounds__(256) void gemm_bt(
    const _Float16* __restrict__ A, const _Float16* __restrict__ Bm,
    const float* __restrict__ bias, float* __restrict__ Cout,
    _Float16* __restrict__ Qo, _Float16* __restrict__ Ko, _Float16* __restrict__ Vto,
    int Ndim, int Kdim) {
  __shared__ __align__(16) _Float16 As[128][40];
  __shared__ __align__(16) _Float16 Bs[128][40];
  const int tid = threadIdx.x;
  const int lane = tid & 63;
  const int wave = tid >> 6;
  const int wm = wave >> 1, wn = wave & 1;
  const int m0 = blockIdx.y * 128, n0 = blockIdx.x * 128;
  const int r = tid >> 2;
  const int kc = (tid & 3) * 8;
  const int row = lane & 15;
  const int kk = (lane >> 4) * 8;

  f32x4 acc[4][4];
#pragma unroll
  for (int i = 0; i < 4; ++i)
#pragma unroll
    for (int j = 0; j < 4; ++j)
#pragma unroll
      for (int q = 0; q < 4; ++q) acc[i][j][q] = 0.f;

  for (int k0 = 0; k0 < Kdim; k0 += 32) {
    *reinterpret_cast<uint4*>(&As[r][kc]) =
        *reinterpret_cast<const uint4*>(&A[(size_t)(m0 + r) * Kdim + k0 + kc]);
    *reinterpret_cast<uint4*>(&As[r + 64][kc]) =
        *reinterpret_cast<const uint4*>(&A[(size_t)(m0 + r + 64) * Kdim + k0 + kc]);
    *reinterpret_cast<uint4*>(&Bs[r][kc]) =
        *reinterpret_cast<const uint4*>(&Bm[(size_t)(n0 + r) * Kdim + k0 + kc]);
    *reinterpret_cast<uint4*>(&Bs[r + 64][kc]) =
        *reinterpret_cast<const uint4*>(&Bm[(size_t)(n0 + r + 64) * Kdim + k0 + kc]);
    __syncthreads();
    f16x8 af[4], bf[4];
#pragma unroll
    for (int i = 0; i < 4; ++i)
      af[i] = *reinterpret_cast<const f16x8*>(&As[wm * 64 + i * 16 + row][kk]);
#pragma unroll
    for (int j = 0; j < 4; ++j)
      bf[j] = *reinterpret_cast<const f16x8*>(&Bs[wn * 64 + j * 16 + row][kk]);
#pragma unroll
    for (int i = 0; i < 4; ++i)
#pragma unroll
      for (int j = 0; j < 4; ++j)
        acc[i][j] = __builtin_amdgcn_mfma_f32_16x16x32_f16(af[i], bf[j], acc[i][j], 0, 0, 0);
    __syncthreads();
  }

#pragma unroll
  for (int i = 0; i < 4; ++i) {
#pragma unroll
    for (int j = 0; j < 4; ++j) {
#pragma unroll
      for (int q = 0; q < 4; ++q) {
        const int gm = m0 + wm * 64 + i * 16 + (lane >> 4) * 4 + q;
        const int gn = n0 + wn * 64 + j * 16 + row;
        const float c = acc[i][j][q] + bias[gn];
        if (EPI == 1) {
          Cout[(size_t)gm * Ndim + gn] = c;
        } else {
          const int b = gm >> 11, l = gm & 2047;
          const int part = gn >> 10, dD = gn & 1023;
          const int h = dD >> 6, dd = dD & 63;
          const int bh = b * 16 + h;
          if (part == 0)
            Qo[((size_t)bh * 2048 + l) * 64 + dd] = (_Float16)(c * 0.125f);  // fold 1/sqrt(hd)
          else if (part == 1)
            Ko[((size_t)bh * 2048 + l) * 64 + dd] = (_Float16)c;
          else
            Vto[((size_t)bh * 64 + dd) * 2048 + l] = (_Float16)c;
        }
      }
    }
  }
}

// ---------------------------------------------------------------- flash attention v3
// v2 register math (swapped QK^T, lane-local softmax, K=16 PV with matching B-frag
// layout) + cooperative double-buffered LDS staging of K/V tiles (one copy per
// block, not per wave) + XOR-swizzled K tile + XCD-clustered block remap.
// grid: 1024 blocks = 32 bh * 32 qtiles, 4 waves/block, wave owns 16 q-rows.
__global__ __launch_bounds__(256) void attn_fwd(const _Float16* __restrict__ Qh,
                                                const _Float16* __restrict__ Kh,
                                                const _Float16* __restrict__ Vth,
                                                _Float16* __restrict__ AOh) {
  // [buf][0..255]   = K tile: 32 rows x 8 granules(16B), granule slot = G ^ (row&7)
  // [buf][256..511] = V^T tile: granule (cc,hd) at 256 + cc*64 + hd  (cc=kv16B-chunk, hd=0..63)
  __shared__ __align__(16) uint4 KVs[2][512];
  const int tid = threadIdx.x, lane = tid & 63, wave = tid >> 6;
  const int bid = blockIdx.x;
  const int bh = (bid & 7) * 4 + ((bid >> 3) & 3);  // 4 bh per XCD -> K/V L2-resident
  const int q0 = (bid >> 5) * 64 + wave * 16;
  const int b = bh >> 4, h = bh & 15;
  const _Float16* Qp = Qh + ((size_t)bh * 2048 + q0) * 64;
  const _Float16* Kp = Kh + (size_t)bh * 2048 * 64;
  const _Float16* Vp = Vth + (size_t)bh * 64 * 2048;
  const int r16 = lane & 15, g = lane >> 4;
  const int kk8 = g * 8, kk4 = g * 4;

  // ---- staging assignment (each thread: 1 K granule + 1 V granule per tile)
  const int krow = tid >> 3;                // 0..31
  const int kslot = tid & 7;                // swizzled LDS slot
  const int kG = kslot ^ (krow & 7);        // source 16B chunk within row
  const _Float16* ksrc = Kp + (size_t)krow * 64 + kG * 8;
  const int vcc = tid & 3, vhd = tid >> 2;  // 16B kv-chunk, hd row
  const _Float16* vsrc = Vp + (size_t)vhd * 2048 + vcc * 8;
  const int vgran = 256 + vcc * 64 + vhd;

  // ---- Q fragments (B-frag: lane holds Q[q=r16][kk8..kk8+7], +32 second half)
  const f16x8 qf0 = *reinterpret_cast<const f16x8*>(&Qp[r16 * 64 + kk8]);
  const f16x8 qf1 = *reinterpret_cast<const f16x8*>(&Qp[r16 * 64 + 32 + kk8]);

  f32x4 o[4];  // O^T acc: o[n][reg] = O^T[hd=n*16+kk4+reg][q=r16]
#pragma unroll
  for (int n = 0; n < 4; ++n)
#pragma unroll
    for (int q = 0; q < 4; ++q) o[n][q] = 0.f;
  float mrun = -1e30f, lrun = 0.f;

  // ---- prologue: stage tile 0
  KVs[0][tid] = *reinterpret_cast<const uint4*>(ksrc);
  KVs[0][vgran] = *reinterpret_cast<const uint4*>(vsrc);

  for (int t = 0; t < 64; ++t) {
    __syncthreads();  // KVs[t&1] ready; all reads of KVs[(t&1)^1] from t-1 done
    const uint4* Kb = KVs[t & 1];
    const uint4* Vb = KVs[t & 1] + 256;
    // issue next-tile global loads now; latency hides under this tile's compute
    uint4 knew = {0, 0, 0, 0}, vnew = {0, 0, 0, 0};
    if (t < 63) {
      knew = *reinterpret_cast<const uint4*>(ksrc + (size_t)(t + 1) * 2048);
      vnew = *reinterpret_cast<const uint4*>(vsrc + (t + 1) * 32);
    }

    // K frags from LDS (swizzled, conflict-free b128):
    // kc[tt*2+dh] = K[kv + tt*16 + r16][dh*32 + kk8 ..+7]
    f16x8 kc[4];
#pragma unroll
    for (int tt = 0; tt < 2; ++tt)
#pragma unroll
      for (int dh = 0; dh < 2; ++dh) {
        const int rowk = tt * 16 + r16;
        kc[tt * 2 + dh] =
            *reinterpret_cast<const f16x8*>(&Kb[rowk * 8 + ((dh * 4 + g) ^ (r16 & 7))]);
      }

    // S^T = K . Q^T : lane holds S[q=r16][k = kv + tt*16 + kk4 + reg]
    f32x4 s0 = {0.f, 0.f, 0.f, 0.f}, s1 = {0.f, 0.f, 0.f, 0.f};
    s0 = __builtin_amdgcn_mfma_f32_16x16x32_f16(kc[0], qf0, s0, 0, 0, 0);
    s0 = __builtin_amdgcn_mfma_f32_16x16x32_f16(kc[1], qf1, s0, 0, 0, 0);
    s1 = __builtin_amdgcn_mfma_f32_16x16x32_f16(kc[2], qf0, s1, 0, 0, 0);
    s1 = __builtin_amdgcn_mfma_f32_16x16x32_f16(kc[3], qf1, s1, 0, 0, 0);

    // lane-local online softmax for q = r16 (4 lanes share q: xor16, xor32)
    float mt = fmaxf(fmaxf(fmaxf(s0[0], s0[1]), fmaxf(s0[2], s0[3])),
                     fmaxf(fmaxf(s1[0], s1[1]), fmaxf(s1[2], s1[3])));
    mt = fmaxf(mt, __shfl_xor(mt, 16));
    mt = fmaxf(mt, __shfl_xor(mt, 32));
    const float mn = fmaxf(mrun, mt);
    const float alpha = __expf(mrun - mn);
    mrun = mn;
    float p[8];
#pragma unroll
    for (int q = 0; q < 4; ++q) p[q] = __expf(s0[q] - mn);
#pragma unroll
    for (int q = 0; q < 4; ++q) p[4 + q] = __expf(s1[q] - mn);
    float rs = ((p[0] + p[1]) + (p[2] + p[3])) + ((p[4] + p[5]) + (p[6] + p[7]));
    rs += __shfl_xor(rs, 16);
    rs += __shfl_xor(rs, 32);
    lrun = lrun * alpha + rs;
#pragma unroll
    for (int n = 0; n < 4; ++n)
#pragma unroll
      for (int q = 0; q < 4; ++q) o[n][q] *= alpha;

    // pack P to f16 (element j of pk_tt is k = kv + tt*16 + kk4 + j == K=16 B-frag)
    f16x4 pk0, pk1;
#pragma unroll
    for (int q = 0; q < 4; ++q) pk0[q] = (_Float16)p[q];
#pragma unroll
    for (int q = 0; q < 4; ++q) pk1[q] = (_Float16)p[4 + q];

    // V frags from LDS: vf[n][tt] = V^T[n*16+r16][kv + tt*16 + kk4 ..+3]
#pragma unroll
    for (int n = 0; n < 4; ++n) {
      f16x4 vf0, vf1;
#pragma unroll
      for (int tt = 0; tt < 2; ++tt) {
        const int cc = tt * 2 + (g >> 1);
        const _Float16* vb16 = reinterpret_cast<const _Float16*>(&Vb[cc * 64 + n * 16 + r16]);
        f16x4 vf = *reinterpret_cast<const f16x4*>(vb16 + (g & 1) * 4);
        if (tt == 0) vf0 = vf; else vf1 = vf;
      }
      o[n] = __builtin_amdgcn_mfma_f32_16x16x16f16(vf0, pk0, o[n], 0, 0, 0);
      o[n] = __builtin_amdgcn_mfma_f32_16x16x16f16(vf1, pk1, o[n], 0, 0, 0);
    }

    // write staged regs -> other LDS buffer (vmcnt satisfied by compute above)
    if (t < 63) {
      KVs[(t & 1) ^ 1][tid] = knew;
      KVs[(t & 1) ^ 1][vgran] = vnew;
    }
  }

  const float inv = 1.f / lrun;
  const size_t grow = (size_t)b * 2048 + q0 + r16;
#pragma unroll
  for (int n = 0; n < 4; ++n) {
    f16x4 c;
#pragma unroll
    for (int q = 0; q < 4; ++q) c[q] = (_Float16)(o[n][q] * inv);
    *reinterpret_cast<f16x4*>(&AOh[grow * 1024 + h * 64 + n * 16 + kk4]) = c;
  }
}

// ---------------------------------------------------------------- launcher
extern "C" void kernel_launch(void* const* d_in, const int* in_sizes, int n_in, void* d_out,
                              int out_size, void* d_ws, size_t ws_size, hipStream_t stream) {
  const float* x = (const float*)d_in[0];
  const float* Wqkv = (const float*)d_in[1];
  const float* bqkv = (const float*)d_in[2];
  const float* Wout = (const float*)d_in[3];
  const float* bout = (const float*)d_in[4];
  float* out = (float*)d_out;

  char* ws = (char*)d_ws;
  _Float16* xh = (_Float16*)(ws);                  // 4096*1024       (8 MB)
  _Float16* wqkvh = (_Float16*)(ws + 8388608);     // 3072*1024       (6 MB)
  _Float16* wouth = (_Float16*)(ws + 14680064);    // 1024*1024       (2 MB)
  _Float16* Qh = (_Float16*)(ws + 16777216);       // [32][2048][64]  (8 MB)
  _Float16* Kh = (_Float16*)(ws + 25165824);       // [32][2048][64]  (8 MB)
  _Float16* Vth = (_Float16*)(ws + 33554432);      // [32][64][2048]  (8 MB)
  _Float16* AOh = (_Float16*)(ws + 41943040);      // 4096*1024       (8 MB)

  cast_f32_f16<<<4096, 256, 0, stream>>>(x, xh, 4194304);
  cast_f32_f16<<<3072, 256, 0, stream>>>(Wqkv, wqkvh, 3145728);
  cast_f32_f16<<<1024, 256, 0, stream>>>(Wout, wouth, 1048576);

  gemm_bt<0><<<dim3(24, 32), 256, 0, stream>>>(xh, wqkvh, bqkv, nullptr, Qh, Kh, Vth, 3072, 1024);
  attn_fwd<<<1024, 256, 0, stream>>>(Qh, Kh, Vth, AOh);
  gemm_bt<1><<<dim3(8, 32), 256, 0, stream>>>(AOh, wouth, bout, out, nullptr, nullptr, nullptr,
                                              1024, 1024);
}

// Round 5
// 160.217 us; speedup vs baseline: 2.6289x; 1.0790x over previous
//
#include <hip/hip_runtime.h>
#include <hip/hip_bf16.h>

typedef __attribute__((ext_vector_type(8))) _Float16 f16x8;
typedef __attribute__((ext_vector_type(4))) _Float16 f16x4;
typedef __attribute__((ext_vector_type(2))) _Float16 f16x2;
typedef __attribute__((ext_vector_type(4))) float f32x4;
typedef __attribute__((ext_vector_type(16))) float f32x16;

__device__ __forceinline__ void gload16(const void* g, void* l) {
  __builtin_amdgcn_global_load_lds((const __attribute__((address_space(1))) void*)g,
                                   (__attribute__((address_space(3))) void*)l, 16, 0, 0);
}
// RNE f16 pair pack
__device__ __forceinline__ unsigned pk2(float a, float b) {
  f16x2 t;
  t[0] = (_Float16)a;
  t[1] = (_Float16)b;
  return __builtin_bit_cast(unsigned, t);
}

// ---------------------------------------------------------------- cast f32 -> f16
__global__ __launch_bounds__(256) void cast_f32_f16(const float* __restrict__ s,
                                                    _Float16* __restrict__ d, int n) {
  int i = (blockIdx.x * blockDim.x + threadIdx.x) * 4;
  if (i >= n) return;
  float4 v = *reinterpret_cast<const float4*>(s + i);
  f16x4 h = {(_Float16)v.x, (_Float16)v.y, (_Float16)v.z, (_Float16)v.w};
  *reinterpret_cast<f16x4*>(d + i) = h;
}

// ---------------------------------------------------------------- GEMM C = A @ B^T + bias
// global_load_lds staging, linear LDS [128][32] (uniform 8-residue b128 reads).
// EPI=0: scatter Q (scaled 0.125*log2e) [bh][L][64], K [bh][L][64], Vt [bh][64][L] (f16)
// EPI=1: Cout[M,N] fp32
template <int EPI>
__global__ __launch_bounds__(256) void gemm_bt(
    const _Float16* __restrict__ A, const _Float16* __restrict__ Bm,
    const float* __restrict__ bias, float* __restrict__ Cout,
    _Float16* __restrict__ Qo, _Float16* __restrict__ Ko, _Float16* __restrict__ Vto,
    int Ndim, int Kdim) {
  __shared__ __align__(16) _Float16 As[128][32];
  __shared__ __align__(16) _Float16 Bs[128][32];
  const int tid = threadIdx.x, lane = tid & 63, wave = tid >> 6;
  const int wm = wave >> 1, wn = wave & 1;
  const int m0 = blockIdx.y * 128, n0 = blockIdx.x * 128;
  const int row = lane & 15, kk = (lane >> 4) * 8;

  // staging: 512 granules per matrix; thread t stages granules t and 256+t
  const int r0 = tid >> 2, c0 = (tid & 3) * 8;
  const int r1 = (256 + tid) >> 2, c1 = ((256 + tid) & 3) * 8;
  const _Float16* a0 = A + (size_t)(m0 + r0) * Kdim + c0;
  const _Float16* a1 = A + (size_t)(m0 + r1) * Kdim + c1;
  const _Float16* b0 = Bm + (size_t)(n0 + r0) * Kdim + c0;
  const _Float16* b1 = Bm + (size_t)(n0 + r1) * Kdim + c1;
  char* dA0 = (char*)As + (wave * 64) * 16;
  char* dA1 = (char*)As + (256 + wave * 64) * 16;
  char* dB0 = (char*)Bs + (wave * 64) * 16;
  char* dB1 = (char*)Bs + (256 + wave * 64) * 16;

  f32x4 acc[4][4];
#pragma unroll
  for (int i = 0; i < 4; ++i)
#pragma unroll
    for (int j = 0; j < 4; ++j)
#pragma unroll
      for (int q = 0; q < 4; ++q) acc[i][j][q] = 0.f;

  for (int k0 = 0; k0 < Kdim; k0 += 32) {
    gload16(a0 + k0, dA0);
    gload16(a1 + k0, dA1);
    gload16(b0 + k0, dB0);
    gload16(b1 + k0, dB1);
    asm volatile("s_waitcnt vmcnt(0)" ::: "memory");
    __syncthreads();
    f16x8 af[4], bf[4];
#pragma unroll
    for (int i = 0; i < 4; ++i)
      af[i] = *reinterpret_cast<const f16x8*>(&As[wm * 64 + i * 16 + row][kk]);
#pragma unroll
    for (int j = 0; j < 4; ++j)
      bf[j] = *reinterpret_cast<const f16x8*>(&Bs[wn * 64 + j * 16 + row][kk]);
#pragma unroll
    for (int i = 0; i < 4; ++i)
#pragma unroll
      for (int j = 0; j < 4; ++j)
        acc[i][j] = __builtin_amdgcn_mfma_f32_16x16x32_f16(af[i], bf[j], acc[i][j], 0, 0, 0);
    __syncthreads();
  }

#pragma unroll
  for (int i = 0; i < 4; ++i) {
#pragma unroll
    for (int j = 0; j < 4; ++j) {
#pragma unroll
      for (int q = 0; q < 4; ++q) {
        const int gm = m0 + wm * 64 + i * 16 + (lane >> 4) * 4 + q;
        const int gn = n0 + wn * 64 + j * 16 + row;
        const float c = acc[i][j][q] + bias[gn];
        if (EPI == 1) {
          Cout[(size_t)gm * Ndim + gn] = c;
        } else {
          const int b = gm >> 11, l = gm & 2047;
          const int part = gn >> 10, dD = gn & 1023;
          const int h = dD >> 6, dd = dD & 63;
          const int bh = b * 16 + h;
          if (part == 0)
            Qo[((size_t)bh * 2048 + l) * 64 + dd] = (_Float16)(c * 0.1803368801f);  // /sqrt(hd)*log2e
          else if (part == 1)
            Ko[((size_t)bh * 2048 + l) * 64 + dd] = (_Float16)c;
          else
            Vto[((size_t)bh * 64 + dd) * 2048 + l] = (_Float16)c;
        }
      }
    }
  }
}

// ---------------------------------------------------------------- flash attention v4b
// 32x32x16 MFMA, 4 waves x 32 q-rows = 128 q/block, KVBLK=64, double-buffered
// global_load_lds K/V staging (XOR-swizzle via pre-swizzled source), lane-local
// log2-domain softmax + defer-max, P words built via __shfl_xor(32)+select
// (verified semantics; replaces direction-ambiguous permlane32_swap).
__global__ __launch_bounds__(256) void attn_fwd(const _Float16* __restrict__ Qh,
                                                const _Float16* __restrict__ Kh,
                                                const _Float16* __restrict__ Vth,
                                                _Float16* __restrict__ AOh) {
  __shared__ __align__(16) uint4 KVs[2][1024];  // [buf][K granules 0..511 | V 512..1023]
  const int tid = threadIdx.x, lane = tid & 63, wave = tid >> 6;
  const int bid = blockIdx.x;
  const int bh = bid & 31, qb = bid >> 5;
  const int b = bh >> 4, h = bh & 15;
  const int q0 = qb * 128 + wave * 32;
  const _Float16* Qp = Qh + ((size_t)bh * 2048 + q0) * 64;
  const _Float16* Kp = Kh + (size_t)bh * 2048 * 64;
  const _Float16* Vp = Vth + (size_t)bh * 64 * 2048;
  const int r31 = lane & 31, hl = lane >> 5, r7 = lane & 7;

  // staging: LDS granule gi = row*8 + slot (linear); source col-granule = slot^(row&7)
  const int kr0 = tid >> 3, ks0 = (tid & 7) ^ (kr0 & 7);
  const int kr1 = (256 + tid) >> 3, ks1 = ((256 + tid) & 7) ^ (kr1 & 7);
  const _Float16* ksrc0 = Kp + (size_t)kr0 * 64 + ks0 * 8;
  const _Float16* ksrc1 = Kp + (size_t)kr1 * 64 + ks1 * 8;
  const _Float16* vsrc0 = Vp + (size_t)kr0 * 2048 + ks0 * 8;
  const _Float16* vsrc1 = Vp + (size_t)kr1 * 2048 + ks1 * 8;

  // Q B-frags: lane holds col q=r31, d = kd*16 + hl*8 + j
  f16x8 qf[4];
#pragma unroll
  for (int kd = 0; kd < 4; ++kd)
    qf[kd] = *reinterpret_cast<const f16x8*>(&Qp[r31 * 64 + kd * 16 + hl * 8]);

  f32x16 o0, o1;  // O^T acc: [hd=(reg&3)+8*(reg>>2)+4*hl+32*hh][q=r31]
#pragma unroll
  for (int i = 0; i < 16; ++i) { o0[i] = 0.f; o1[i] = 0.f; }
  float mrun = -3.0e38f, lrun = 0.f;

  auto STAGE = [&](int buf, int t) {
    uint4* base = &KVs[buf][0];
    gload16(ksrc0 + (size_t)t * 4096, base + wave * 64);
    gload16(ksrc1 + (size_t)t * 4096, base + 256 + wave * 64);
    gload16(vsrc0 + t * 64, base + 512 + wave * 64);
    gload16(vsrc1 + t * 64, base + 768 + wave * 64);
  };

  STAGE(0, 0);
  asm volatile("s_waitcnt vmcnt(0)" ::: "memory");
  __syncthreads();

  for (int t = 0; t < 32; ++t) {
    const int buf = t & 1;
    if (t < 31) STAGE(buf ^ 1, t + 1);
    const char* KB = (const char*)&KVs[buf][0];
    const char* VB = (const char*)&KVs[buf][512];

    // S^T = K . Q^T (two 32x32 kv-tiles, contraction over d=64 in 4 steps)
    f32x16 st[2];
#pragma unroll
    for (int t32 = 0; t32 < 2; ++t32) {
#pragma unroll
      for (int i = 0; i < 16; ++i) st[t32][i] = 0.f;
#pragma unroll
      for (int kd = 0; kd < 4; ++kd) {
        const f16x8 kf = *reinterpret_cast<const f16x8*>(
            KB + (((t32 * 32 + r31) * 8 + ((kd * 2 + hl) ^ r7)) << 4));
        st[t32] = __builtin_amdgcn_mfma_f32_32x32x16_f16(kf, qf[kd], st[t32], 0, 0, 0);
      }
    }

    // V A-frags (issue before softmax; independent)
    f16x8 vf[2][2][2];  // [hh][t32][s]
#pragma unroll
    for (int hh = 0; hh < 2; ++hh)
#pragma unroll
      for (int t32 = 0; t32 < 2; ++t32)
#pragma unroll
        for (int s = 0; s < 2; ++s)
          vf[hh][t32][s] = *reinterpret_cast<const f16x8*>(
              VB + (((hh * 32 + r31) * 8 + (((t32 * 2 + s) * 2 + hl) ^ r7)) << 4));

    // log2-domain online softmax for q=r31 (partner lane l^32 holds complementary rows)
    float mt = st[0][0];
#pragma unroll
    for (int i = 1; i < 16; ++i) mt = fmaxf(mt, st[0][i]);
#pragma unroll
    for (int i = 0; i < 16; ++i) mt = fmaxf(mt, st[1][i]);
    mt = fmaxf(mt, __shfl_xor(mt, 32));
    if (!__all(mt - mrun <= 11.f)) {  // T13 defer-max: P bounded by 2^11, f16-safe
      const float mn = fmaxf(mrun, mt);
      const float al = exp2f(mrun - mn);
      lrun *= al;
#pragma unroll
      for (int i = 0; i < 16; ++i) { o0[i] *= al; o1[i] *= al; }
      mrun = mn;
    }
    float p[2][16];
    float rs = 0.f;
#pragma unroll
    for (int t32 = 0; t32 < 2; ++t32)
#pragma unroll
      for (int i = 0; i < 16; ++i) {
        p[t32][i] = exp2f(st[t32][i] - mrun);
        rs += p[t32][i];
      }
    rs += __shfl_xor(rs, 32);
    lrun += rs;

    // P -> f16 B-frag words. Lane holds P at kv rows crow(reg,hl)=(reg&3)+8*(reg>>2)+4*hl.
    // B-frag word w, elem e: kv_local = hl*8 + 2w + e. Cross-half data via shfl_xor(32):
    //   w0 = hl ? Bx : A      (hl0: own p0,p1 = kv0,1 | hl1: partner-lo p4,p5 = kv8,9)
    //   w2 = hl ? B  : Ax     (hl0: partner-hi p0,p1 = kv4,5 | hl1: own p4,p5 = kv12,13)
#pragma unroll
    for (int t32 = 0; t32 < 2; ++t32) {
#pragma unroll
      for (int s = 0; s < 2; ++s) {
        const unsigned A = pk2(p[t32][s * 8 + 0], p[t32][s * 8 + 1]);
        const unsigned A2 = pk2(p[t32][s * 8 + 2], p[t32][s * 8 + 3]);
        const unsigned B = pk2(p[t32][s * 8 + 4], p[t32][s * 8 + 5]);
        const unsigned B2 = pk2(p[t32][s * 8 + 6], p[t32][s * 8 + 7]);
        const unsigned Ax = __shfl_xor(A, 32), A2x = __shfl_xor(A2, 32);
        const unsigned Bx = __shfl_xor(B, 32), B2x = __shfl_xor(B2, 32);
        union { unsigned u[4]; f16x8 v; } pf;
        pf.u[0] = hl ? Bx : A;
        pf.u[1] = hl ? B2x : A2;
        pf.u[2] = hl ? B : Ax;
        pf.u[3] = hl ? B2 : A2x;
        o0 = __builtin_amdgcn_mfma_f32_32x32x16_f16(vf[0][t32][s], pf.v, o0, 0, 0, 0);
        o1 = __builtin_amdgcn_mfma_f32_32x32x16_f16(vf[1][t32][s], pf.v, o1, 0, 0, 0);
      }
    }

    if (t < 31) {
      asm volatile("s_waitcnt vmcnt(0)" ::: "memory");
      __syncthreads();
    }
  }

  const float inv = 1.f / lrun;
  const size_t orow = (size_t)b * 2048 + q0 + r31;
#pragma unroll
  for (int hh = 0; hh < 2; ++hh) {
#pragma unroll
    for (int rr = 0; rr < 4; ++rr) {
      f16x4 c;
#pragma unroll
      for (int j = 0; j < 4; ++j)
        c[j] = (_Float16)((hh ? o1[rr * 4 + j] : o0[rr * 4 + j]) * inv);
      const int hd = 8 * rr + 4 * hl + 32 * hh;
      *reinterpret_cast<f16x4*>(&AOh[orow * 1024 + h * 64 + hd]) = c;
    }
  }
}

// ---------------------------------------------------------------- launcher
extern "C" void kernel_launch(void* const* d_in, const int* in_sizes, int n_in, void* d_out,
                              int out_size, void* d_ws, size_t ws_size, hipStream_t stream) {
  const float* x = (const float*)d_in[0];
  const float* Wqkv = (const float*)d_in[1];
  const float* bqkv = (const float*)d_in[2];
  const float* Wout = (const float*)d_in[3];
  const float* bout = (const float*)d_in[4];
  float* out = (float*)d_out;

  char* ws = (char*)d_ws;
  _Float16* xh = (_Float16*)(ws);                  // 4096*1024       (8 MB)
  _Float16* wqkvh = (_Float16*)(ws + 8388608);     // 3072*1024       (6 MB)
  _Float16* wouth = (_Float16*)(ws + 14680064);    // 1024*1024       (2 MB)
  _Float16* Qh = (_Float16*)(ws + 16777216);       // [32][2048][64]  (8 MB)
  _Float16* Kh = (_Float16*)(ws + 25165824);       // [32][2048][64]  (8 MB)
  _Float16* Vth = (_Float16*)(ws + 33554432);      // [32][64][2048]  (8 MB)
  _Float16* AOh = (_Float16*)(ws + 41943040);      // 4096*1024       (8 MB)

  cast_f32_f16<<<4096, 256, 0, stream>>>(x, xh, 4194304);
  cast_f32_f16<<<3072, 256, 0, stream>>>(Wqkv, wqkvh, 3145728);
  cast_f32_f16<<<1024, 256, 0, stream>>>(Wout, wouth, 1048576);

  gemm_bt<0><<<dim3(24, 32), 256, 0, stream>>>(xh, wqkvh, bqkv, nullptr, Qh, Kh, Vth, 3072, 1024);
  attn_fwd<<<512, 256, 0, stream>>>(Qh, Kh, Vth, AOh);
  gemm_bt<1><<<dim3(8, 32), 256, 0, stream>>>(AOh, wouth, bout, out, nullptr, nullptr, nullptr,
                                              1024, 1024);
}

// Round 6
// 157.101 us; speedup vs baseline: 2.6810x; 1.0198x over previous
//
#include <hip/hip_runtime.h>
#include <hip/hip_bf16.h>

typedef __attribute__((ext_vector_type(8))) _Float16 f16x8;
typedef __attribute__((ext_vector_type(4))) _Float16 f16x4;
typedef __attribute__((ext_vector_type(2))) _Float16 f16x2;
typedef __attribute__((ext_vector_type(4))) float f32x4;
typedef __attribute__((ext_vector_type(16))) float f32x16;

__device__ __forceinline__ void gload16(const void* g, void* l) {
  __builtin_amdgcn_global_load_lds((const __attribute__((address_space(1))) void*)g,
                                   (__attribute__((address_space(3))) void*)l, 16, 0, 0);
}
// RNE f16 pair pack
__device__ __forceinline__ unsigned pk2(float a, float b) {
  f16x2 t;
  t[0] = (_Float16)a;
  t[1] = (_Float16)b;
  return __builtin_bit_cast(unsigned, t);
}

// ---------------------------------------------------------------- cast f32 -> f16
__global__ __launch_bounds__(256) void cast_f32_f16(const float* __restrict__ s,
                                                    _Float16* __restrict__ d, int n) {
  int i = (blockIdx.x * blockDim.x + threadIdx.x) * 4;
  if (i >= n) return;
  float4 v = *reinterpret_cast<const float4*>(s + i);
  f16x4 h = {(_Float16)v.x, (_Float16)v.y, (_Float16)v.z, (_Float16)v.w};
  *reinterpret_cast<f16x4*>(d + i) = h;
}

// ---------------------------------------------------------------- GEMM C = A @ B^T + bias
// Double-buffered global_load_lds staging (T3-minimum 2-phase: STAGE(t+1) before
// compute(t), one drain+barrier per K-step). Linear LDS [128][32].
// EPI=0: scatter Q (scaled 0.125*log2e) [bh][L][64], K [bh][L][64], Vt [bh][64][L] (f16)
// EPI=1: Cout[M,N] fp32
template <int EPI>
__global__ __launch_bounds__(256) void gemm_bt(
    const _Float16* __restrict__ A, const _Float16* __restrict__ Bm,
    const float* __restrict__ bias, float* __restrict__ Cout,
    _Float16* __restrict__ Qo, _Float16* __restrict__ Ko, _Float16* __restrict__ Vto,
    int Ndim, int Kdim) {
  __shared__ __align__(16) _Float16 As[2][128 * 32];
  __shared__ __align__(16) _Float16 Bs[2][128 * 32];
  const int tid = threadIdx.x, lane = tid & 63, wave = tid >> 6;
  const int wm = wave >> 1, wn = wave & 1;
  const int m0 = blockIdx.y * 128, n0 = blockIdx.x * 128;
  const int row = lane & 15, kk = (lane >> 4) * 8;

  // staging: 512 granules per matrix; thread t stages granules t and 256+t
  const int r0 = tid >> 2, c0 = (tid & 3) * 8;
  const int r1 = (256 + tid) >> 2, c1 = ((256 + tid) & 3) * 8;
  const _Float16* a0 = A + (size_t)(m0 + r0) * Kdim + c0;
  const _Float16* a1 = A + (size_t)(m0 + r1) * Kdim + c1;
  const _Float16* b0 = Bm + (size_t)(n0 + r0) * Kdim + c0;
  const _Float16* b1 = Bm + (size_t)(n0 + r1) * Kdim + c1;

  f32x4 acc[4][4];
#pragma unroll
  for (int i = 0; i < 4; ++i)
#pragma unroll
    for (int j = 0; j < 4; ++j)
#pragma unroll
      for (int q = 0; q < 4; ++q) acc[i][j][q] = 0.f;

  auto STAGE = [&](int bufi, int k0) {
    char* dA = (char*)&As[bufi][0] + (wave * 64) * 16;
    char* dB = (char*)&Bs[bufi][0] + (wave * 64) * 16;
    gload16(a0 + k0, dA);
    gload16(a1 + k0, dA + 4096);
    gload16(b0 + k0, dB);
    gload16(b1 + k0, dB + 4096);
  };

  STAGE(0, 0);
  asm volatile("s_waitcnt vmcnt(0)" ::: "memory");
  __syncthreads();

  for (int k0 = 0; k0 < Kdim; k0 += 32) {
    const int cur = (k0 >> 5) & 1;
    if (k0 + 32 < Kdim) STAGE(cur ^ 1, k0 + 32);
    f16x8 af[4], bf[4];
#pragma unroll
    for (int i = 0; i < 4; ++i)
      af[i] = *reinterpret_cast<const f16x8*>(&As[cur][(wm * 64 + i * 16 + row) * 32 + kk]);
#pragma unroll
    for (int j = 0; j < 4; ++j)
      bf[j] = *reinterpret_cast<const f16x8*>(&Bs[cur][(wn * 64 + j * 16 + row) * 32 + kk]);
#pragma unroll
    for (int i = 0; i < 4; ++i)
#pragma unroll
      for (int j = 0; j < 4; ++j)
        acc[i][j] = __builtin_amdgcn_mfma_f32_16x16x32_f16(af[i], bf[j], acc[i][j], 0, 0, 0);
    asm volatile("s_waitcnt vmcnt(0)" ::: "memory");
    __syncthreads();
  }

#pragma unroll
  for (int i = 0; i < 4; ++i) {
#pragma unroll
    for (int j = 0; j < 4; ++j) {
#pragma unroll
      for (int q = 0; q < 4; ++q) {
        const int gm = m0 + wm * 64 + i * 16 + (lane >> 4) * 4 + q;
        const int gn = n0 + wn * 64 + j * 16 + row;
        const float c = acc[i][j][q] + bias[gn];
        if (EPI == 1) {
          Cout[(size_t)gm * Ndim + gn] = c;
        } else {
          const int b = gm >> 11, l = gm & 2047;
          const int part = gn >> 10, dD = gn & 1023;
          const int h = dD >> 6, dd = dD & 63;
          const int bh = b * 16 + h;
          if (part == 0)
            Qo[((size_t)bh * 2048 + l) * 64 + dd] = (_Float16)(c * 0.1803368801f);  // /sqrt(hd)*log2e
          else if (part == 1)
            Ko[((size_t)bh * 2048 + l) * 64 + dd] = (_Float16)c;
          else
            Vto[((size_t)bh * 64 + dd) * 2048 + l] = (_Float16)c;
        }
      }
    }
  }
}

// ---------------------------------------------------------------- flash attention v5
// Split-KV x2: 1024 blocks = 32 bh * 16 qb * 2 kv-halves; each block does 1024 kv
// (16 iters of 64). Partial (m, l, O/l) stored per half; merged by attn_combine.
// 32x32x16 MFMA, lane-local log2 softmax, defer-max (lane-local check), 2-shfl
// P exchange, lane-local l-sum.
__global__ __launch_bounds__(256) void attn_fwd(const _Float16* __restrict__ Qh,
                                                const _Float16* __restrict__ Kh,
                                                const _Float16* __restrict__ Vth,
                                                _Float16* __restrict__ AO0,
                                                _Float16* __restrict__ AO1,
                                                float2* __restrict__ ml) {
  __shared__ __align__(16) uint4 KVs[2][1024];  // [buf][K granules 0..511 | V 512..1023]
  const int tid = threadIdx.x, lane = tid & 63, wave = tid >> 6;
  const int bid = blockIdx.x;
  const int bh = bid & 31;            // bid%8 = bh%8 -> 4 bh per XCD, K/V L2-resident
  const int rest = bid >> 5;
  const int qb = rest >> 1, kvh = rest & 1;
  const int b = bh >> 4, h = bh & 15;
  const int q0 = qb * 128 + wave * 32;
  const _Float16* Qp = Qh + ((size_t)bh * 2048 + q0) * 64;
  const _Float16* Kp = Kh + (size_t)bh * 2048 * 64 + (size_t)kvh * 1024 * 64;
  const _Float16* Vp = Vth + (size_t)bh * 64 * 2048 + kvh * 1024;
  const int r31 = lane & 31, hl = lane >> 5, r7 = lane & 7;

  // staging: LDS granule gi = row*8 + slot (linear); source col-granule = slot^(row&7)
  const int kr0 = tid >> 3, ks0 = (tid & 7) ^ (kr0 & 7);
  const int kr1 = (256 + tid) >> 3, ks1 = ((256 + tid) & 7) ^ (kr1 & 7);
  const _Float16* ksrc0 = Kp + (size_t)kr0 * 64 + ks0 * 8;
  const _Float16* ksrc1 = Kp + (size_t)kr1 * 64 + ks1 * 8;
  const _Float16* vsrc0 = Vp + (size_t)kr0 * 2048 + ks0 * 8;
  const _Float16* vsrc1 = Vp + (size_t)kr1 * 2048 + ks1 * 8;

  // Q B-frags: lane holds col q=r31, d = kd*16 + hl*8 + j
  f16x8 qf[4];
#pragma unroll
  for (int kd = 0; kd < 4; ++kd)
    qf[kd] = *reinterpret_cast<const f16x8*>(&Qp[r31 * 64 + kd * 16 + hl * 8]);

  f32x16 o0, o1;  // O^T acc: [hd=(reg&3)+8*(reg>>2)+4*hl+32*hh][q=r31]
#pragma unroll
  for (int i = 0; i < 16; ++i) { o0[i] = 0.f; o1[i] = 0.f; }
  float mrun = -3.0e38f, lsum = 0.f;

  auto STAGE = [&](int buf, int t) {
    uint4* base = &KVs[buf][0];
    gload16(ksrc0 + (size_t)t * 4096, base + wave * 64);
    gload16(ksrc1 + (size_t)t * 4096, base + 256 + wave * 64);
    gload16(vsrc0 + t * 64, base + 512 + wave * 64);
    gload16(vsrc1 + t * 64, base + 768 + wave * 64);
  };

  STAGE(0, 0);
  asm volatile("s_waitcnt vmcnt(0)" ::: "memory");
  __syncthreads();

  for (int t = 0; t < 16; ++t) {
    const int buf = t & 1;
    if (t < 15) STAGE(buf ^ 1, t + 1);
    const char* KB = (const char*)&KVs[buf][0];
    const char* VB = (const char*)&KVs[buf][512];

    // S^T = K . Q^T (two 32x32 kv-tiles, contraction over d=64 in 4 steps)
    f32x16 st[2];
#pragma unroll
    for (int t32 = 0; t32 < 2; ++t32) {
#pragma unroll
      for (int i = 0; i < 16; ++i) st[t32][i] = 0.f;
#pragma unroll
      for (int kd = 0; kd < 4; ++kd) {
        const f16x8 kf = *reinterpret_cast<const f16x8*>(
            KB + (((t32 * 32 + r31) * 8 + ((kd * 2 + hl) ^ r7)) << 4));
        st[t32] = __builtin_amdgcn_mfma_f32_32x32x16_f16(kf, qf[kd], st[t32], 0, 0, 0);
      }
    }

    // V A-frags (issue before softmax; independent)
    f16x8 vf[2][2][2];  // [hh][t32][s]
#pragma unroll
    for (int hh = 0; hh < 2; ++hh)
#pragma unroll
      for (int t32 = 0; t32 < 2; ++t32)
#pragma unroll
        for (int s = 0; s < 2; ++s)
          vf[hh][t32][s] = *reinterpret_cast<const f16x8*>(
              VB + (((hh * 32 + r31) * 8 + (((t32 * 2 + s) * 2 + hl) ^ r7)) << 4));

    // lane-local tree max over this lane's 32 P-elements
    float a[16];
#pragma unroll
    for (int i = 0; i < 16; ++i) a[i] = fmaxf(st[0][i], st[1][i]);
#pragma unroll
    for (int w = 8; w; w >>= 1)
#pragma unroll
      for (int i = 0; i < 8; ++i)
        if (i < w) a[i] = fmaxf(a[i], a[i + w]);
    const float mt = a[0];
    // defer-max (T13): rescale only when some lane exceeds threshold (wave-uniform)
    if (!__all(mt - mrun <= 11.f)) {
      const float mts = fmaxf(mt, __shfl_xor(mt, 32));  // symmetric over kv of col q=r31
      const float mn = fmaxf(mrun, mts);
      const float al = exp2f(mrun - mn);
      lsum *= al;
#pragma unroll
      for (int i = 0; i < 16; ++i) { o0[i] *= al; o1[i] *= al; }
      mrun = mn;
    }
    float p[2][16];
    float rs = 0.f;
#pragma unroll
    for (int t32 = 0; t32 < 2; ++t32)
#pragma unroll
      for (int i = 0; i < 16; ++i) {
        p[t32][i] = exp2f(st[t32][i] - mrun);
        rs += p[t32][i];
      }
    lsum += rs;  // lane-local; combined with partner once at end

    // P -> f16 B-frag words. Lane holds kv rows crow(reg,hl)=(reg&3)+8*(reg>>2)+4*hl.
    // hl0 needs partner's A,A2 (kv4..7); hl1 needs partner's B,B2 (kv8..11):
    // send = hl ? A* : B*, one shfl_xor(32) serves both directions.
#pragma unroll
    for (int t32 = 0; t32 < 2; ++t32) {
#pragma unroll
      for (int s = 0; s < 2; ++s) {
        const unsigned A = pk2(p[t32][s * 8 + 0], p[t32][s * 8 + 1]);
        const unsigned A2 = pk2(p[t32][s * 8 + 2], p[t32][s * 8 + 3]);
        const unsigned B = pk2(p[t32][s * 8 + 4], p[t32][s * 8 + 5]);
        const unsigned B2 = pk2(p[t32][s * 8 + 6], p[t32][s * 8 + 7]);
        const unsigned r1 = __shfl_xor(hl ? A : B, 32);   // hl0<-Ax, hl1<-Bx
        const unsigned r2 = __shfl_xor(hl ? A2 : B2, 32); // hl0<-A2x, hl1<-B2x
        union { unsigned u[4]; f16x8 v; } pf;
        pf.u[0] = hl ? r1 : A;
        pf.u[1] = hl ? r2 : A2;
        pf.u[2] = hl ? B : r1;
        pf.u[3] = hl ? B2 : r2;
        o0 = __builtin_amdgcn_mfma_f32_32x32x16_f16(vf[0][t32][s], pf.v, o0, 0, 0, 0);
        o1 = __builtin_amdgcn_mfma_f32_32x32x16_f16(vf[1][t32][s], pf.v, o1, 0, 0, 0);
      }
    }

    if (t < 15) {
      asm volatile("s_waitcnt vmcnt(0)" ::: "memory");
      __syncthreads();
    }
  }

  const float ltot = lsum + __shfl_xor(lsum, 32);
  const float inv = 1.f / ltot;
  _Float16* AOp = kvh ? AO1 : AO0;
  const size_t orow = (size_t)b * 2048 + q0 + r31;
#pragma unroll
  for (int hh = 0; hh < 2; ++hh) {
#pragma unroll
    for (int rr = 0; rr < 4; ++rr) {
      f16x4 c;
#pragma unroll
      for (int j = 0; j < 4; ++j)
        c[j] = (_Float16)((hh ? o1[rr * 4 + j] : o0[rr * 4 + j]) * inv);
      const int hd = 8 * rr + 4 * hl + 32 * hh;
      *reinterpret_cast<f16x4*>(&AOp[orow * 1024 + h * 64 + hd]) = c;
    }
  }
  if (hl == 0) ml[kvh * 65536 + bh * 2048 + q0 + r31] = make_float2(mrun, ltot);
}

// ---------------------------------------------------------------- split-KV merge
// O = w0*O0 + w1*O1, w_i = l_i*2^(m_i-m*) / sum. In-place into AO0.
__global__ __launch_bounds__(256) void attn_combine(const _Float16* __restrict__ AO1,
                                                    const float2* __restrict__ ml,
                                                    _Float16* __restrict__ AO0) {
  const int idx = (blockIdx.x * 256 + threadIdx.x) * 8;  // over 4096*1024
  const int row = idx >> 10, col = idx & 1023;
  const int b = row >> 11, l = row & 2047, h = col >> 6;
  const int bh = b * 16 + h;
  const float2 m0 = ml[bh * 2048 + l];
  const float2 m1 = ml[65536 + bh * 2048 + l];
  const float ms = fmaxf(m0.x, m1.x);
  float w0 = m0.y * exp2f(m0.x - ms);
  float w1 = m1.y * exp2f(m1.x - ms);
  const float inv = 1.f / (w0 + w1);
  w0 *= inv;
  w1 *= inv;
  const f16x8 a = *reinterpret_cast<const f16x8*>(AO0 + idx);
  const f16x8 c = *reinterpret_cast<const f16x8*>(AO1 + idx);
  f16x8 r;
#pragma unroll
  for (int j = 0; j < 8; ++j) r[j] = (_Float16)(w0 * (float)a[j] + w1 * (float)c[j]);
  *reinterpret_cast<f16x8*>(AO0 + idx) = r;
}

// ---------------------------------------------------------------- launcher
extern "C" void kernel_launch(void* const* d_in, const int* in_sizes, int n_in, void* d_out,
                              int out_size, void* d_ws, size_t ws_size, hipStream_t stream) {
  const float* x = (const float*)d_in[0];
  const float* Wqkv = (const float*)d_in[1];
  const float* bqkv = (const float*)d_in[2];
  const float* Wout = (const float*)d_in[3];
  const float* bout = (const float*)d_in[4];
  float* out = (float*)d_out;

  char* ws = (char*)d_ws;
  _Float16* xh = (_Float16*)(ws);                  // 4096*1024 (8 MB), dead after gemm<0>
  _Float16* wqkvh = (_Float16*)(ws + 8388608);     // 3072*1024 (6 MB), dead after gemm<0>
  _Float16* wouth = (_Float16*)(ws + 14680064);    // 1024*1024 (2 MB)
  _Float16* Qh = (_Float16*)(ws + 16777216);       // [32][2048][64] (8 MB)
  _Float16* Kh = (_Float16*)(ws + 25165824);       // [32][2048][64] (8 MB)
  _Float16* Vth = (_Float16*)(ws + 33554432);      // [32][64][2048] (8 MB)
  _Float16* AO0 = (_Float16*)(ws + 41943040);      // 4096*1024 (8 MB), partial 0 + merged
  _Float16* AO1 = (_Float16*)(ws);                 // reuse xh region: partial 1
  float2* ml = (float2*)(ws + 8388608);            // reuse wqkvh region: [2][32][2048] (1 MB)

  cast_f32_f16<<<4096, 256, 0, stream>>>(x, xh, 4194304);
  cast_f32_f16<<<3072, 256, 0, stream>>>(Wqkv, wqkvh, 3145728);
  cast_f32_f16<<<1024, 256, 0, stream>>>(Wout, wouth, 1048576);

  gemm_bt<0><<<dim3(24, 32), 256, 0, stream>>>(xh, wqkvh, bqkv, nullptr, Qh, Kh, Vth, 3072, 1024);
  attn_fwd<<<1024, 256, 0, stream>>>(Qh, Kh, Vth, AO0, AO1, ml);
  attn_combine<<<2048, 256, 0, stream>>>(AO1, ml, AO0);
  gemm_bt<1><<<dim3(8, 32), 256, 0, stream>>>(AO0, wouth, bout, out, nullptr, nullptr, nullptr,
                                              1024, 1024);
}

// Round 7
// 142.579 us; speedup vs baseline: 2.9541x; 1.1018x over previous
//
#include <hip/hip_runtime.h>
#include <hip/hip_bf16.h>

typedef __attribute__((ext_vector_type(8))) _Float16 f16x8;
typedef __attribute__((ext_vector_type(4))) _Float16 f16x4;
typedef __attribute__((ext_vector_type(2))) _Float16 f16x2;
typedef __attribute__((ext_vector_type(4))) float f32x4;
typedef __attribute__((ext_vector_type(16))) float f32x16;

__device__ __forceinline__ void gload16(const void* g, void* l) {
  __builtin_amdgcn_global_load_lds((const __attribute__((address_space(1))) void*)g,
                                   (__attribute__((address_space(3))) void*)l, 16, 0, 0);
}
// RNE f16 pair pack (zero-mean rounding; RTZ would bias PV vs fp32 l-sum)
__device__ __forceinline__ unsigned pk2(float a, float b) {
  f16x2 t;
  t[0] = (_Float16)a;
  t[1] = (_Float16)b;
  return __builtin_bit_cast(unsigned, t);
}

// ---------------------------------------------------------------- fused casts f32 -> f16
// covers x (4194304), W_qkv (3145728), W_out (1048576); segment bounds are
// multiples of the 2048-elem per-block span, so no straddle.
__global__ __launch_bounds__(256) void cast_all(const float* __restrict__ x,
                                                const float* __restrict__ wqkv,
                                                const float* __restrict__ wout,
                                                _Float16* __restrict__ xh,
                                                _Float16* __restrict__ wqkvh,
                                                _Float16* __restrict__ wouth) {
  const int i = (blockIdx.x * 256 + threadIdx.x) * 8;
  const float* s;
  _Float16* d;
  int off;
  if (i < 4194304) {
    s = x; d = xh; off = i;
  } else if (i < 7340032) {
    s = wqkv; d = wqkvh; off = i - 4194304;
  } else {
    s = wout; d = wouth; off = i - 7340032;
  }
  const float4 v0 = *reinterpret_cast<const float4*>(s + off);
  const float4 v1 = *reinterpret_cast<const float4*>(s + off + 4);
  f16x8 h;
  h[0] = (_Float16)v0.x; h[1] = (_Float16)v0.y; h[2] = (_Float16)v0.z; h[3] = (_Float16)v0.w;
  h[4] = (_Float16)v1.x; h[5] = (_Float16)v1.y; h[6] = (_Float16)v1.z; h[7] = (_Float16)v1.w;
  *reinterpret_cast<f16x8*>(d + off) = h;
}

// ---------------------------------------------------------------- GEMM C = A @ B^T + bias
// Double-buffered global_load_lds staging (2-phase). Linear LDS [128][32].
// EPI=0: scatter Q (scaled 0.125*log2e) [bh][L][64], K [bh][L][64], Vt [bh][64][L] (f16)
// EPI=1: Cout[M,N] fp32
template <int EPI>
__global__ __launch_bounds__(256) void gemm_bt(
    const _Float16* __restrict__ A, const _Float16* __restrict__ Bm,
    const float* __restrict__ bias, float* __restrict__ Cout,
    _Float16* __restrict__ Qo, _Float16* __restrict__ Ko, _Float16* __restrict__ Vto,
    int Ndim, int Kdim) {
  __shared__ __align__(16) _Float16 As[2][128 * 32];
  __shared__ __align__(16) _Float16 Bs[2][128 * 32];
  const int tid = threadIdx.x, lane = tid & 63, wave = tid >> 6;
  const int wm = wave >> 1, wn = wave & 1;
  const int m0 = blockIdx.y * 128, n0 = blockIdx.x * 128;
  const int row = lane & 15, kk = (lane >> 4) * 8;

  const int r0 = tid >> 2, c0 = (tid & 3) * 8;
  const int r1 = (256 + tid) >> 2, c1 = ((256 + tid) & 3) * 8;
  const _Float16* a0 = A + (size_t)(m0 + r0) * Kdim + c0;
  const _Float16* a1 = A + (size_t)(m0 + r1) * Kdim + c1;
  const _Float16* b0 = Bm + (size_t)(n0 + r0) * Kdim + c0;
  const _Float16* b1 = Bm + (size_t)(n0 + r1) * Kdim + c1;

  f32x4 acc[4][4];
#pragma unroll
  for (int i = 0; i < 4; ++i)
#pragma unroll
    for (int j = 0; j < 4; ++j)
#pragma unroll
      for (int q = 0; q < 4; ++q) acc[i][j][q] = 0.f;

  auto STAGE = [&](int bufi, int k0) {
    char* dA = (char*)&As[bufi][0] + (wave * 64) * 16;
    char* dB = (char*)&Bs[bufi][0] + (wave * 64) * 16;
    gload16(a0 + k0, dA);
    gload16(a1 + k0, dA + 4096);
    gload16(b0 + k0, dB);
    gload16(b1 + k0, dB + 4096);
  };

  STAGE(0, 0);
  asm volatile("s_waitcnt vmcnt(0)" ::: "memory");
  __syncthreads();

  for (int k0 = 0; k0 < Kdim; k0 += 32) {
    const int cur = (k0 >> 5) & 1;
    if (k0 + 32 < Kdim) STAGE(cur ^ 1, k0 + 32);
    f16x8 af[4], bf[4];
#pragma unroll
    for (int i = 0; i < 4; ++i)
      af[i] = *reinterpret_cast<const f16x8*>(&As[cur][(wm * 64 + i * 16 + row) * 32 + kk]);
#pragma unroll
    for (int j = 0; j < 4; ++j)
      bf[j] = *reinterpret_cast<const f16x8*>(&Bs[cur][(wn * 64 + j * 16 + row) * 32 + kk]);
#pragma unroll
    for (int i = 0; i < 4; ++i)
#pragma unroll
      for (int j = 0; j < 4; ++j)
        acc[i][j] = __builtin_amdgcn_mfma_f32_16x16x32_f16(af[i], bf[j], acc[i][j], 0, 0, 0);
    asm volatile("s_waitcnt vmcnt(0)" ::: "memory");
    __syncthreads();
  }

#pragma unroll
  for (int i = 0; i < 4; ++i) {
#pragma unroll
    for (int j = 0; j < 4; ++j) {
#pragma unroll
      for (int q = 0; q < 4; ++q) {
        const int gm = m0 + wm * 64 + i * 16 + (lane >> 4) * 4 + q;
        const int gn = n0 + wn * 64 + j * 16 + row;
        const float c = acc[i][j][q] + bias[gn];
        if (EPI == 1) {
          Cout[(size_t)gm * Ndim + gn] = c;
        } else {
          const int b = gm >> 11, l = gm & 2047;
          const int part = gn >> 10, dD = gn & 1023;
          const int h = dD >> 6, dd = dD & 63;
          const int bh = b * 16 + h;
          if (part == 0)
            Qo[((size_t)bh * 2048 + l) * 64 + dd] = (_Float16)(c * 0.1803368801f);  // /sqrt(hd)*log2e
          else if (part == 1)
            Ko[((size_t)bh * 2048 + l) * 64 + dd] = (_Float16)c;
          else
            Vto[((size_t)bh * 64 + dd) * 2048 + l] = (_Float16)c;
        }
      }
    }
  }
}

// ---------------------------------------------------------------- flash attention v6
// Single-pass (2048 kv, 32 iters of 64). 32x32x16 MFMA, 4 waves x 32 q-rows.
// __launch_bounds__(256,2): full register budget, no AGPR spill/remat in hot loop
// (R6 evidence: occupancy doesn't pay; register ILP does). Pair-unrolled buffers,
// setprio around MFMA clusters, max3-fused reductions.
__global__ __launch_bounds__(256, 2) void attn_fwd(const _Float16* __restrict__ Qh,
                                                   const _Float16* __restrict__ Kh,
                                                   const _Float16* __restrict__ Vth,
                                                   _Float16* __restrict__ AOh) {
  __shared__ __align__(16) uint4 KVs[2][1024];  // [buf][K granules 0..511 | V 512..1023]
  const int tid = threadIdx.x, lane = tid & 63, wave = tid >> 6;
  const int bid = blockIdx.x;
  const int bh = bid & 31, qb = bid >> 5;  // bid%8 = bh%8 -> 4 bh per XCD
  const int b = bh >> 4, h = bh & 15;
  const int q0 = qb * 128 + wave * 32;
  const _Float16* Qp = Qh + ((size_t)bh * 2048 + q0) * 64;
  const _Float16* Kp = Kh + (size_t)bh * 2048 * 64;
  const _Float16* Vp = Vth + (size_t)bh * 64 * 2048;
  const int r31 = lane & 31, hl = lane >> 5, r7 = lane & 7;

  // staging: LDS granule gi = row*8 + slot (linear); source col-granule = slot^(row&7)
  const int kr0 = tid >> 3, ks0 = (tid & 7) ^ (kr0 & 7);
  const int kr1 = (256 + tid) >> 3, ks1 = ((256 + tid) & 7) ^ (kr1 & 7);
  const _Float16* ksrc0 = Kp + (size_t)kr0 * 64 + ks0 * 8;
  const _Float16* ksrc1 = Kp + (size_t)kr1 * 64 + ks1 * 8;
  const _Float16* vsrc0 = Vp + (size_t)kr0 * 2048 + ks0 * 8;
  const _Float16* vsrc1 = Vp + (size_t)kr1 * 2048 + ks1 * 8;

  // Q B-frags: lane holds col q=r31, d = kd*16 + hl*8 + j
  f16x8 qf[4];
#pragma unroll
  for (int kd = 0; kd < 4; ++kd)
    qf[kd] = *reinterpret_cast<const f16x8*>(&Qp[r31 * 64 + kd * 16 + hl * 8]);

  f32x16 o0, o1;  // O^T acc: [hd=(reg&3)+8*(reg>>2)+4*hl+32*hh][q=r31]
#pragma unroll
  for (int i = 0; i < 16; ++i) { o0[i] = 0.f; o1[i] = 0.f; }
  float mrun = -3.0e38f, lsum = 0.f;

  auto STAGE = [&](uint4* base, int t) {
    gload16(ksrc0 + (size_t)t * 4096, base + wave * 64);
    gload16(ksrc1 + (size_t)t * 4096, base + 256 + wave * 64);
    gload16(vsrc0 + t * 64, base + 512 + wave * 64);
    gload16(vsrc1 + t * 64, base + 768 + wave * 64);
  };

  auto ITER = [&](int t, uint4* cur, uint4* nxt) {
    if (t < 31) STAGE(nxt, t + 1);
    const char* KB = (const char*)cur;
    const char* VB = (const char*)(cur + 512);

    // S^T = K . Q^T (two 32x32 kv-tiles, contraction over d=64 in 4 steps)
    f32x16 st[2];
    __builtin_amdgcn_s_setprio(1);
#pragma unroll
    for (int t32 = 0; t32 < 2; ++t32) {
#pragma unroll
      for (int i = 0; i < 16; ++i) st[t32][i] = 0.f;
#pragma unroll
      for (int kd = 0; kd < 4; ++kd) {
        const f16x8 kf = *reinterpret_cast<const f16x8*>(
            KB + (((t32 * 32 + r31) * 8 + ((kd * 2 + hl) ^ r7)) << 4));
        st[t32] = __builtin_amdgcn_mfma_f32_32x32x16_f16(kf, qf[kd], st[t32], 0, 0, 0);
      }
    }
    __builtin_amdgcn_s_setprio(0);

    // V A-frags (issue before softmax; lgkm waits land before PV)
    f16x8 vf[2][2][2];  // [hh][t32][s]
#pragma unroll
    for (int hh = 0; hh < 2; ++hh)
#pragma unroll
      for (int t32 = 0; t32 < 2; ++t32)
#pragma unroll
        for (int s = 0; s < 2; ++s)
          vf[hh][t32][s] = *reinterpret_cast<const f16x8*>(
              VB + (((hh * 32 + r31) * 8 + (((t32 * 2 + s) * 2 + hl) ^ r7)) << 4));

    // lane-local max via two max3 chains
    float ma = fmaxf(st[0][0], st[0][1]);
    float mb = fmaxf(st[1][0], st[1][1]);
#pragma unroll
    for (int i = 2; i < 16; i += 2) {
      ma = fmaxf(fmaxf(st[0][i], st[0][i + 1]), ma);
      mb = fmaxf(fmaxf(st[1][i], st[1][i + 1]), mb);
    }
    const float mt = fmaxf(ma, mb);
    // defer-max (T13): rescale only when some lane's tile-max exceeds mrun+11
    if (!__all(mt - mrun <= 11.f)) {
      const float mts = fmaxf(mt, __shfl_xor(mt, 32));
      const float mn = fmaxf(mrun, mts);
      const float al = exp2f(mrun - mn);
      lsum *= al;
#pragma unroll
      for (int i = 0; i < 16; ++i) { o0[i] *= al; o1[i] *= al; }
      mrun = mn;
    }
    float pr[32];
    float rs = 0.f;
#pragma unroll
    for (int i = 0; i < 16; ++i) {
      pr[i] = exp2f(st[0][i] - mrun);
      rs += pr[i];
    }
#pragma unroll
    for (int i = 0; i < 16; ++i) {
      pr[16 + i] = exp2f(st[1][i] - mrun);
      rs += pr[16 + i];
    }
    lsum += rs;  // lane-local; partner-combined once at end

    // P -> f16 B-frag words; one-shfl-per-pair exchange across lane^32, then PV.
    __builtin_amdgcn_s_setprio(1);
#pragma unroll
    for (int t32 = 0; t32 < 2; ++t32) {
#pragma unroll
      for (int s = 0; s < 2; ++s) {
        const int bi = t32 * 16 + s * 8;
        const unsigned Aw = pk2(pr[bi + 0], pr[bi + 1]);
        const unsigned A2 = pk2(pr[bi + 2], pr[bi + 3]);
        const unsigned Bw = pk2(pr[bi + 4], pr[bi + 5]);
        const unsigned B2 = pk2(pr[bi + 6], pr[bi + 7]);
        const unsigned r1 = __shfl_xor(hl ? Aw : Bw, 32);
        const unsigned r2 = __shfl_xor(hl ? A2 : B2, 32);
        union { unsigned u[4]; f16x8 v; } pf;
        pf.u[0] = hl ? r1 : Aw;
        pf.u[1] = hl ? r2 : A2;
        pf.u[2] = hl ? Bw : r1;
        pf.u[3] = hl ? B2 : r2;
        o0 = __builtin_amdgcn_mfma_f32_32x32x16_f16(vf[0][t32][s], pf.v, o0, 0, 0, 0);
        o1 = __builtin_amdgcn_mfma_f32_32x32x16_f16(vf[1][t32][s], pf.v, o1, 0, 0, 0);
      }
    }
    __builtin_amdgcn_s_setprio(0);

    if (t < 31) {
      asm volatile("s_waitcnt vmcnt(0)" ::: "memory");
      __syncthreads();
    }
  };

  STAGE(KVs[0], 0);
  asm volatile("s_waitcnt vmcnt(0)" ::: "memory");
  __syncthreads();

  for (int tt = 0; tt < 16; ++tt) {
    ITER(2 * tt, KVs[0], KVs[1]);
    ITER(2 * tt + 1, KVs[1], KVs[0]);
  }

  const float ltot = lsum + __shfl_xor(lsum, 32);
  const float inv = 1.f / ltot;
  const size_t orow = (size_t)b * 2048 + q0 + r31;
#pragma unroll
  for (int hh = 0; hh < 2; ++hh) {
#pragma unroll
    for (int rr = 0; rr < 4; ++rr) {
      f16x4 c;
#pragma unroll
      for (int j = 0; j < 4; ++j)
        c[j] = (_Float16)((hh ? o1[rr * 4 + j] : o0[rr * 4 + j]) * inv);
      const int hd = 8 * rr + 4 * hl + 32 * hh;
      *reinterpret_cast<f16x4*>(&AOh[orow * 1024 + h * 64 + hd]) = c;
    }
  }
}

// ---------------------------------------------------------------- launcher
extern "C" void kernel_launch(void* const* d_in, const int* in_sizes, int n_in, void* d_out,
                              int out_size, void* d_ws, size_t ws_size, hipStream_t stream) {
  const float* x = (const float*)d_in[0];
  const float* Wqkv = (const float*)d_in[1];
  const float* bqkv = (const float*)d_in[2];
  const float* Wout = (const float*)d_in[3];
  const float* bout = (const float*)d_in[4];
  float* out = (float*)d_out;

  char* ws = (char*)d_ws;
  _Float16* xh = (_Float16*)(ws);                  // 4096*1024 (8 MB)
  _Float16* wqkvh = (_Float16*)(ws + 8388608);     // 3072*1024 (6 MB)
  _Float16* wouth = (_Float16*)(ws + 14680064);    // 1024*1024 (2 MB)
  _Float16* Qh = (_Float16*)(ws + 16777216);       // [32][2048][64] (8 MB)
  _Float16* Kh = (_Float16*)(ws + 25165824);       // [32][2048][64] (8 MB)
  _Float16* Vth = (_Float16*)(ws + 33554432);      // [32][64][2048] (8 MB)
  _Float16* AOh = (_Float16*)(ws + 41943040);      // 4096*1024 (8 MB)

  cast_all<<<4096, 256, 0, stream>>>(x, Wqkv, Wout, xh, wqkvh, wouth);
  gemm_bt<0><<<dim3(24, 32), 256, 0, stream>>>(xh, wqkvh, bqkv, nullptr, Qh, Kh, Vth, 3072, 1024);
  attn_fwd<<<512, 256, 0, stream>>>(Qh, Kh, Vth, AOh);
  gemm_bt<1><<<dim3(8, 32), 256, 0, stream>>>(AOh, wouth, bout, out, nullptr, nullptr, nullptr,
                                              1024, 1024);
}

// Round 8
// 126.877 us; speedup vs baseline: 3.3196x; 1.1238x over previous
//
#include <hip/hip_runtime.h>
#include <hip/hip_bf16.h>

typedef __attribute__((ext_vector_type(8))) _Float16 f16x8;
typedef __attribute__((ext_vector_type(4))) _Float16 f16x4;
typedef __attribute__((ext_vector_type(2))) _Float16 f16x2;
typedef __attribute__((ext_vector_type(4))) float f32x4;
typedef __attribute__((ext_vector_type(16))) float f32x16;
typedef __attribute__((ext_vector_type(2))) __fp16 fp16v2;

__device__ __forceinline__ void gload16(const void* g, void* l) {
  __builtin_amdgcn_global_load_lds((const __attribute__((address_space(1))) void*)g,
                                   (__attribute__((address_space(3))) void*)l, 16, 0, 0);
}
// raw v_exp_f32 (2^x); exp2f without fast-math lowers to a guarded libm sequence
__device__ __forceinline__ float fexp2(float x) {
#if __has_builtin(__builtin_amdgcn_exp2f)
  return __builtin_amdgcn_exp2f(x);
#else
  return exp2f(x);
#endif
}
// single-instruction f32x2 -> f16x2 pack (RTZ)
__device__ __forceinline__ unsigned pk2(float a, float b) {
#if __has_builtin(__builtin_amdgcn_cvt_pkrtz)
  fp16v2 r = __builtin_amdgcn_cvt_pkrtz(a, b);
  return __builtin_bit_cast(unsigned, r);
#else
  f16x2 t;
  t[0] = (_Float16)a;
  t[1] = (_Float16)b;
  return __builtin_bit_cast(unsigned, t);
#endif
}

// ---------------------------------------------------------------- fused casts f32 -> f16
__global__ __launch_bounds__(256) void cast_all(const float* __restrict__ x,
                                                const float* __restrict__ wqkv,
                                                const float* __restrict__ wout,
                                                _Float16* __restrict__ xh,
                                                _Float16* __restrict__ wqkvh,
                                                _Float16* __restrict__ wouth) {
  const int i = (blockIdx.x * 256 + threadIdx.x) * 8;
  const float* s;
  _Float16* d;
  int off;
  if (i < 4194304) {
    s = x; d = xh; off = i;
  } else if (i < 7340032) {
    s = wqkv; d = wqkvh; off = i - 4194304;
  } else {
    s = wout; d = wouth; off = i - 7340032;
  }
  const float4 v0 = *reinterpret_cast<const float4*>(s + off);
  const float4 v1 = *reinterpret_cast<const float4*>(s + off + 4);
  f16x8 h;
  h[0] = (_Float16)v0.x; h[1] = (_Float16)v0.y; h[2] = (_Float16)v0.z; h[3] = (_Float16)v0.w;
  h[4] = (_Float16)v1.x; h[5] = (_Float16)v1.y; h[6] = (_Float16)v1.z; h[7] = (_Float16)v1.w;
  *reinterpret_cast<f16x8*>(d + off) = h;
}

// ---------------------------------------------------------------- GEMM C = A @ B^T + bias
// Double-buffered global_load_lds staging, linear LDS [128][32], XCD-bijective
// block swizzle (nwg % 8 == 0 for both call sites).
template <int EPI>
__global__ __launch_bounds__(256) void gemm_bt(
    const _Float16* __restrict__ A, const _Float16* __restrict__ Bm,
    const float* __restrict__ bias, float* __restrict__ Cout,
    _Float16* __restrict__ Qo, _Float16* __restrict__ Ko, _Float16* __restrict__ Vto,
    int Ndim, int Kdim) {
  __shared__ __align__(16) _Float16 As[2][128 * 32];
  __shared__ __align__(16) _Float16 Bs[2][128 * 32];
  const int tid = threadIdx.x, lane = tid & 63, wave = tid >> 6;
  const int wm = wave >> 1, wn = wave & 1;
  // XCD swizzle: contiguous chunk of the linear grid per XCD
  const int nwg = gridDim.x * gridDim.y;
  int bidl = blockIdx.y * gridDim.x + blockIdx.x;
  bidl = (bidl & 7) * (nwg >> 3) + (bidl >> 3);
  const int m0 = (bidl / gridDim.x) * 128, n0 = (bidl % gridDim.x) * 128;
  const int row = lane & 15, kk = (lane >> 4) * 8;

  const int r0 = tid >> 2, c0 = (tid & 3) * 8;
  const int r1 = (256 + tid) >> 2, c1 = ((256 + tid) & 3) * 8;
  const _Float16* a0 = A + (size_t)(m0 + r0) * Kdim + c0;
  const _Float16* a1 = A + (size_t)(m0 + r1) * Kdim + c1;
  const _Float16* b0 = Bm + (size_t)(n0 + r0) * Kdim + c0;
  const _Float16* b1 = Bm + (size_t)(n0 + r1) * Kdim + c1;

  f32x4 acc[4][4];
#pragma unroll
  for (int i = 0; i < 4; ++i)
#pragma unroll
    for (int j = 0; j < 4; ++j)
#pragma unroll
      for (int q = 0; q < 4; ++q) acc[i][j][q] = 0.f;

  auto STAGE = [&](int bufi, int k0) {
    char* dA = (char*)&As[bufi][0] + (wave * 64) * 16;
    char* dB = (char*)&Bs[bufi][0] + (wave * 64) * 16;
    gload16(a0 + k0, dA);
    gload16(a1 + k0, dA + 4096);
    gload16(b0 + k0, dB);
    gload16(b1 + k0, dB + 4096);
  };

  STAGE(0, 0);
  asm volatile("s_waitcnt vmcnt(0)" ::: "memory");
  __syncthreads();

  for (int k0 = 0; k0 < Kdim; k0 += 32) {
    const int cur = (k0 >> 5) & 1;
    if (k0 + 32 < Kdim) STAGE(cur ^ 1, k0 + 32);
    f16x8 af[4], bf[4];
#pragma unroll
    for (int i = 0; i < 4; ++i)
      af[i] = *reinterpret_cast<const f16x8*>(&As[cur][(wm * 64 + i * 16 + row) * 32 + kk]);
#pragma unroll
    for (int j = 0; j < 4; ++j)
      bf[j] = *reinterpret_cast<const f16x8*>(&Bs[cur][(wn * 64 + j * 16 + row) * 32 + kk]);
#pragma unroll
    for (int i = 0; i < 4; ++i)
#pragma unroll
      for (int j = 0; j < 4; ++j)
        acc[i][j] = __builtin_amdgcn_mfma_f32_16x16x32_f16(af[i], bf[j], acc[i][j], 0, 0, 0);
    asm volatile("s_waitcnt vmcnt(0)" ::: "memory");
    __syncthreads();
  }

#pragma unroll
  for (int i = 0; i < 4; ++i) {
#pragma unroll
    for (int j = 0; j < 4; ++j) {
#pragma unroll
      for (int q = 0; q < 4; ++q) {
        const int gm = m0 + wm * 64 + i * 16 + (lane >> 4) * 4 + q;
        const int gn = n0 + wn * 64 + j * 16 + row;
        const float c = acc[i][j][q] + bias[gn];
        if (EPI == 1) {
          Cout[(size_t)gm * Ndim + gn] = c;
        } else {
          const int b = gm >> 11, l = gm & 2047;
          const int part = gn >> 10, dD = gn & 1023;
          const int h = dD >> 6, dd = dD & 63;
          const int bh = b * 16 + h;
          if (part == 0)
            Qo[((size_t)bh * 2048 + l) * 64 + dd] = (_Float16)(c * 0.1803368801f);  // /sqrt(hd)*log2e
          else if (part == 1)
            Ko[((size_t)bh * 2048 + l) * 64 + dd] = (_Float16)c;
          else
            Vto[((size_t)bh * 64 + dd) * 2048 + l] = (_Float16)c;
        }
      }
    }
  }
}

// ---------------------------------------------------------------- flash attention v7
// v6 structure + VALU diet: raw v_exp_f32, cvt_pkrtz P-pack, -mrun folded into the
// QK^T accumulator init (subs only in rare rescale branch), tree max/sum.
__global__ __launch_bounds__(256, 2) void attn_fwd(const _Float16* __restrict__ Qh,
                                                   const _Float16* __restrict__ Kh,
                                                   const _Float16* __restrict__ Vth,
                                                   _Float16* __restrict__ AOh) {
  __shared__ __align__(16) uint4 KVs[2][1024];  // [buf][K granules 0..511 | V 512..1023]
  const int tid = threadIdx.x, lane = tid & 63, wave = tid >> 6;
  const int bid = blockIdx.x;
  const int bh = bid & 31, qb = bid >> 5;  // bid%8 = bh%8 -> 4 bh per XCD
  const int b = bh >> 4, h = bh & 15;
  const int q0 = qb * 128 + wave * 32;
  const _Float16* Qp = Qh + ((size_t)bh * 2048 + q0) * 64;
  const _Float16* Kp = Kh + (size_t)bh * 2048 * 64;
  const _Float16* Vp = Vth + (size_t)bh * 64 * 2048;
  const int r31 = lane & 31, hl = lane >> 5, r7 = lane & 7;

  const int kr0 = tid >> 3, ks0 = (tid & 7) ^ (kr0 & 7);
  const int kr1 = (256 + tid) >> 3, ks1 = ((256 + tid) & 7) ^ (kr1 & 7);
  const _Float16* ksrc0 = Kp + (size_t)kr0 * 64 + ks0 * 8;
  const _Float16* ksrc1 = Kp + (size_t)kr1 * 64 + ks1 * 8;
  const _Float16* vsrc0 = Vp + (size_t)kr0 * 2048 + ks0 * 8;
  const _Float16* vsrc1 = Vp + (size_t)kr1 * 2048 + ks1 * 8;

  // Q B-frags: lane holds col q=r31, d = kd*16 + hl*8 + j
  f16x8 qf[4];
#pragma unroll
  for (int kd = 0; kd < 4; ++kd)
    qf[kd] = *reinterpret_cast<const f16x8*>(&Qp[r31 * 64 + kd * 16 + hl * 8]);

  f32x16 o0, o1;  // O^T acc: [hd=(reg&3)+8*(reg>>2)+4*hl+32*hh][q=r31]
#pragma unroll
  for (int i = 0; i < 16; ++i) { o0[i] = 0.f; o1[i] = 0.f; }
  // mrun = running max in log2 domain; init 0 is safe (lsum=0 -> no phantom mass,
  // scores |S|~O(30); defer bound keeps P <= 2^11 for f16)
  float mrun = 0.f, lsum = 0.f;

  auto STAGE = [&](uint4* base, int t) {
    gload16(ksrc0 + (size_t)t * 4096, base + wave * 64);
    gload16(ksrc1 + (size_t)t * 4096, base + 256 + wave * 64);
    gload16(vsrc0 + t * 64, base + 512 + wave * 64);
    gload16(vsrc1 + t * 64, base + 768 + wave * 64);
  };

  auto ITER = [&](int t, uint4* cur, uint4* nxt) {
    if (t < 31) STAGE(nxt, t + 1);
    const char* KB = (const char*)cur;
    const char* VB = (const char*)(cur + 512);

    // S^T - mrun = K . Q^T + (-mrun): fold the softmax shift into the C-init
    const float negm = -mrun;
    f32x16 st[2];
    __builtin_amdgcn_s_setprio(1);
#pragma unroll
    for (int t32 = 0; t32 < 2; ++t32) {
#pragma unroll
      for (int i = 0; i < 16; ++i) st[t32][i] = negm;
#pragma unroll
      for (int kd = 0; kd < 4; ++kd) {
        const f16x8 kf = *reinterpret_cast<const f16x8*>(
            KB + (((t32 * 32 + r31) * 8 + ((kd * 2 + hl) ^ r7)) << 4));
        st[t32] = __builtin_amdgcn_mfma_f32_32x32x16_f16(kf, qf[kd], st[t32], 0, 0, 0);
      }
    }
    __builtin_amdgcn_s_setprio(0);

    // V A-frags
    f16x8 vf[2][2][2];  // [hh][t32][s]
#pragma unroll
    for (int hh = 0; hh < 2; ++hh)
#pragma unroll
      for (int t32 = 0; t32 < 2; ++t32)
#pragma unroll
        for (int s = 0; s < 2; ++s)
          vf[hh][t32][s] = *reinterpret_cast<const f16x8*>(
              VB + (((hh * 32 + r31) * 8 + (((t32 * 2 + s) * 2 + hl) ^ r7)) << 4));

    // tree max over the lane's 32 shifted scores
    float m16[16];
#pragma unroll
    for (int i = 0; i < 16; ++i) m16[i] = fmaxf(st[0][i], st[1][i]);
#pragma unroll
    for (int w = 8; w; w >>= 1)
#pragma unroll
      for (int i = 0; i < 8; ++i)
        if (i < w) m16[i] = fmaxf(m16[i], m16[i + w]);
    const float mt = m16[0];
    // defer-max (T13): rescale only when some lane's tile-max exceeds +11
    if (!__all(mt <= 11.f)) {
      const float mts = fmaxf(mt, __shfl_xor(mt, 32));
      const float d = fmaxf(mts, 0.f);
      const float al = fexp2(-d);
      lsum *= al;
#pragma unroll
      for (int i = 0; i < 16; ++i) { o0[i] *= al; o1[i] *= al; }
      mrun += d;
#pragma unroll
      for (int t32 = 0; t32 < 2; ++t32)
#pragma unroll
        for (int i = 0; i < 16; ++i) st[t32][i] -= d;
    }
    // P = 2^st (single v_exp_f32 each), f32 tree-sum for l
    float pr[32];
#pragma unroll
    for (int i = 0; i < 16; ++i) pr[i] = fexp2(st[0][i]);
#pragma unroll
    for (int i = 0; i < 16; ++i) pr[16 + i] = fexp2(st[1][i]);
    float s16[16];
#pragma unroll
    for (int i = 0; i < 16; ++i) s16[i] = pr[i] + pr[16 + i];
#pragma unroll
    for (int w = 8; w; w >>= 1)
#pragma unroll
      for (int i = 0; i < 8; ++i)
        if (i < w) s16[i] += s16[i + w];
    lsum += s16[0];

    // P -> f16 B-frag words (cvt_pkrtz); one-shfl-per-pair exchange across lane^32
    __builtin_amdgcn_s_setprio(1);
#pragma unroll
    for (int t32 = 0; t32 < 2; ++t32) {
#pragma unroll
      for (int s = 0; s < 2; ++s) {
        const int bi = t32 * 16 + s * 8;
        const unsigned Aw = pk2(pr[bi + 0], pr[bi + 1]);
        const unsigned A2 = pk2(pr[bi + 2], pr[bi + 3]);
        const unsigned Bw = pk2(pr[bi + 4], pr[bi + 5]);
        const unsigned B2 = pk2(pr[bi + 6], pr[bi + 7]);
        const unsigned r1 = __shfl_xor(hl ? Aw : Bw, 32);
        const unsigned r2 = __shfl_xor(hl ? A2 : B2, 32);
        union { unsigned u[4]; f16x8 v; } pf;
        pf.u[0] = hl ? r1 : Aw;
        pf.u[1] = hl ? r2 : A2;
        pf.u[2] = hl ? Bw : r1;
        pf.u[3] = hl ? B2 : r2;
        o0 = __builtin_amdgcn_mfma_f32_32x32x16_f16(vf[0][t32][s], pf.v, o0, 0, 0, 0);
        o1 = __builtin_amdgcn_mfma_f32_32x32x16_f16(vf[1][t32][s], pf.v, o1, 0, 0, 0);
      }
    }
    __builtin_amdgcn_s_setprio(0);

    if (t < 31) {
      asm volatile("s_waitcnt vmcnt(0)" ::: "memory");
      __syncthreads();
    }
  };

  STAGE(KVs[0], 0);
  asm volatile("s_waitcnt vmcnt(0)" ::: "memory");
  __syncthreads();

  for (int tt = 0; tt < 16; ++tt) {
    ITER(2 * tt, KVs[0], KVs[1]);
    ITER(2 * tt + 1, KVs[1], KVs[0]);
  }

  const float ltot = lsum + __shfl_xor(lsum, 32);
  const float inv = 1.f / ltot;
  const size_t orow = (size_t)b * 2048 + q0 + r31;
#pragma unroll
  for (int hh = 0; hh < 2; ++hh) {
#pragma unroll
    for (int rr = 0; rr < 4; ++rr) {
      f16x4 c;
#pragma unroll
      for (int j = 0; j < 4; ++j)
        c[j] = (_Float16)((hh ? o1[rr * 4 + j] : o0[rr * 4 + j]) * inv);
      const int hd = 8 * rr + 4 * hl + 32 * hh;
      *reinterpret_cast<f16x4*>(&AOh[orow * 1024 + h * 64 + hd]) = c;
    }
  }
}

// ---------------------------------------------------------------- launcher
extern "C" void kernel_launch(void* const* d_in, const int* in_sizes, int n_in, void* d_out,
                              int out_size, void* d_ws, size_t ws_size, hipStream_t stream) {
  const float* x = (const float*)d_in[0];
  const float* Wqkv = (const float*)d_in[1];
  const float* bqkv = (const float*)d_in[2];
  const float* Wout = (const float*)d_in[3];
  const float* bout = (const float*)d_in[4];
  float* out = (float*)d_out;

  char* ws = (char*)d_ws;
  _Float16* xh = (_Float16*)(ws);                  // 4096*1024 (8 MB)
  _Float16* wqkvh = (_Float16*)(ws + 8388608);     // 3072*1024 (6 MB)
  _Float16* wouth = (_Float16*)(ws + 14680064);    // 1024*1024 (2 MB)
  _Float16* Qh = (_Float16*)(ws + 16777216);       // [32][2048][64] (8 MB)
  _Float16* Kh = (_Float16*)(ws + 25165824);       // [32][2048][64] (8 MB)
  _Float16* Vth = (_Float16*)(ws + 33554432);      // [32][64][2048] (8 MB)
  _Float16* AOh = (_Float16*)(ws + 41943040);      // 4096*1024 (8 MB)

  cast_all<<<4096, 256, 0, stream>>>(x, Wqkv, Wout, xh, wqkvh, wouth);
  gemm_bt<0><<<dim3(24, 32), 256, 0, stream>>>(xh, wqkvh, bqkv, nullptr, Qh, Kh, Vth, 3072, 1024);
  attn_fwd<<<512, 256, 0, stream>>>(Qh, Kh, Vth, AOh);
  gemm_bt<1><<<dim3(8, 32), 256, 0, stream>>>(AOh, wouth, bout, out, nullptr, nullptr, nullptr,
                                              1024, 1024);
}